// Round 1
// baseline (645.509 us; speedup 1.0000x reference)
//
#include <hip/hip_runtime.h>

// Problem constants (B=16, D=128, H=32, W=32, K=8192)
#define D 128
#define HW 1024
#define NROWS 16384
#define K 8192
#define TILE_R 64
#define TILE_C 64
#define ZSTR 132   // 128 + 4 pad: keeps float4 alignment, breaks pow2 bank stride

// d_out layout (float offsets): z_q_st | indices | new_codebook | new_count | new_weight
#define OUT0 0
#define OUT1 2097152
#define OUT2 2113536
#define OUT3 3162112
#define OUT4 3170304

__global__ __launch_bounds__(256) void k_cnorm(const float* __restrict__ cb,
                                               float* __restrict__ cnorm) {
    int lane = threadIdx.x & 63;
    int k = blockIdx.x * 4 + (threadIdx.x >> 6);
    float2 v = *(const float2*)(cb + k * D + lane * 2);
    float s = v.x * v.x + v.y * v.y;
#pragma unroll
    for (int off = 32; off > 0; off >>= 1) s += __shfl_down(s, off);
    if (lane == 0) cnorm[k] = s;
}

__global__ __launch_bounds__(256) void k_argmin(const float* __restrict__ z_e,
                                                const float* __restrict__ cb,
                                                const float* __restrict__ cnorm,
                                                unsigned long long* __restrict__ packed) {
    __shared__ float Zt[TILE_R * ZSTR];
    __shared__ float Ct[TILE_C * ZSTR];
    __shared__ float cnS[TILE_C];

    const int tid = threadIdx.x;
    const int tileId = blockIdx.x >> 1;   // 256 row tiles
    const int khalf = blockIdx.x & 1;     // split K for 2 blocks/CU occupancy
    const int n0 = tileId * TILE_R;
    const int bb = n0 >> 10;
    const int p0 = n0 & 1023;
    const float* zb = z_e + bb * (D * HW) + p0;

    // Stage Z tile: global is d-major (r contiguous) -> LDS r-major (d contiguous)
    for (int i = tid; i < 2048; i += 256) {
        int d = i >> 4;
        int r4 = (i & 15) << 2;
        float4 v = *(const float4*)(zb + d * HW + r4);
        Zt[(r4 + 0) * ZSTR + d] = v.x;
        Zt[(r4 + 1) * ZSTR + d] = v.y;
        Zt[(r4 + 2) * ZSTR + d] = v.z;
        Zt[(r4 + 3) * ZSTR + d] = v.w;
    }

    const int tx = tid & 15, ty = tid >> 4;
    float minv[4];
    int mini[4];
#pragma unroll
    for (int j = 0; j < 4; ++j) { minv[j] = INFINITY; mini[j] = 0; }

    const int k0 = khalf * (K / 2);
    __syncthreads();

    for (int kt = 0; kt < (K / 2) / TILE_C; ++kt) {
        const int kbase = k0 + kt * TILE_C;
        // Stage code tile (row-major already d-contiguous)
        for (int i = tid; i < 2048; i += 256) {
            int c = i >> 5;
            int d4 = (i & 31) << 2;
            *(float4*)(&Ct[c * ZSTR + d4]) = *(const float4*)(cb + (kbase + c) * D + d4);
        }
        if (tid < TILE_C) cnS[tid] = cnorm[kbase + tid];
        __syncthreads();

        float acc[4][4] = {{0.f, 0.f, 0.f, 0.f}};
#pragma unroll 4
        for (int d4 = 0; d4 < D; d4 += 4) {
            float4 a[4], b[4];
#pragma unroll
            for (int j = 0; j < 4; ++j)
                a[j] = *(const float4*)(&Zt[(ty + 16 * j) * ZSTR + d4]);
#pragma unroll
            for (int j = 0; j < 4; ++j)
                b[j] = *(const float4*)(&Ct[(tx + 16 * j) * ZSTR + d4]);
#pragma unroll
            for (int jr = 0; jr < 4; ++jr)
#pragma unroll
                for (int jc = 0; jc < 4; ++jc) {
                    acc[jr][jc] = fmaf(a[jr].x, b[jc].x, acc[jr][jc]);
                    acc[jr][jc] = fmaf(a[jr].y, b[jc].y, acc[jr][jc]);
                    acc[jr][jc] = fmaf(a[jr].z, b[jc].z, acc[jr][jc]);
                    acc[jr][jc] = fmaf(a[jr].w, b[jc].w, acc[jr][jc]);
                }
        }

        float cn[4];
#pragma unroll
        for (int jc = 0; jc < 4; ++jc) cn[jc] = cnS[tx + 16 * jc];
#pragma unroll
        for (int jr = 0; jr < 4; ++jr)
#pragma unroll
            for (int jc = 0; jc < 4; ++jc) {
                float vd = cn[jc] - 2.0f * acc[jr][jc];
                int kk = kbase + tx + 16 * jc;   // ascending k within thread -> strict < keeps lowest
                if (vd < minv[jr]) { minv[jr] = vd; mini[jr] = kk; }
            }
        __syncthreads();
    }

    // Reduce across the 16 tx lanes sharing each row (contiguous lanes in wave)
#pragma unroll
    for (int jr = 0; jr < 4; ++jr) {
        float v = minv[jr];
        int ix = mini[jr];
#pragma unroll
        for (int off = 1; off < 16; off <<= 1) {
            float v2 = __shfl_xor(v, off);
            int i2 = __shfl_xor(ix, off);
            if (v2 < v || (v2 == v && i2 < ix)) { v = v2; ix = i2; }
        }
        if (tx == 0) {
            // monotonic fp32 -> u32 encoding, idx in low 13 bits: min == (min dist, then min idx)
            unsigned int u = __float_as_uint(v);
            u = (u & 0x80000000u) ? ~u : (u | 0x80000000u);
            unsigned long long pk = ((unsigned long long)u << 13) | (unsigned long long)(unsigned)ix;
            atomicMin(&packed[n0 + ty + 16 * jr], pk);
        }
    }
}

__global__ __launch_bounds__(256) void k_epilogue(const float* __restrict__ z_e,
                                                  const float* __restrict__ cb,
                                                  const unsigned long long* __restrict__ packed,
                                                  float* __restrict__ out0,
                                                  float* __restrict__ out1,
                                                  float* __restrict__ counts,
                                                  float* __restrict__ dw) {
    __shared__ int idxS[TILE_R];
    const int tid = threadIdx.x;
    const int n0 = blockIdx.x * TILE_R;
    const int bb = n0 >> 10, p0 = n0 & 1023;

    if (tid < TILE_R) {
        int ix = (int)(packed[n0 + tid] & 0x1FFFull);
        idxS[tid] = ix;
        out1[n0 + tid] = (float)ix;
        atomicAdd(&counts[ix], 1.0f);
    }
    __syncthreads();

    const float* zb = z_e + bb * (D * HW) + p0;
    float* ob = out0 + bb * (D * HW) + p0;

    // z_q_st: coalesced writes (fixed d, r contiguous); mimic z + (z_q - z) exactly
    for (int i = tid; i < TILE_R * D; i += 256) {
        int d = i >> 6, r = i & 63;
        float z = zb[d * HW + r];
        float c = cb[idxS[r] * D + d];
        ob[d * HW + r] = z + (c - z);
    }
    // dw scatter: r-major so atomics hit consecutive addresses (coalescable)
    for (int i = tid; i < TILE_R * D; i += 256) {
        int r = i >> 7, d = i & 127;
        atomicAdd(&dw[idxS[r] * D + d], zb[d * HW + r]);
    }
}

__global__ __launch_bounds__(256) void k_final(const float* __restrict__ ema_count,
                                               const float* __restrict__ ema_weight,
                                               float* __restrict__ out2,
                                               float* __restrict__ out3,
                                               float* __restrict__ out4) {
    int gid = blockIdx.x * 256 + threadIdx.x;   // over K*D
    int k = gid >> 7, d = gid & 127;
    float cnt_raw = out3[k];    // raw counts (both codes of this block are fully inside it)
    float dw_raw = out4[gid];   // raw dw
    __syncthreads();            // all raw reads before any in-place write
    float nc = 0.99f * ema_count[k] + 0.01f * cnt_raw;
    float nw = 0.99f * ema_weight[gid] + 0.01f * dw_raw;
    out4[gid] = nw;
    out2[gid] = nw / fmaxf(nc, 1.0f);
    if (d == 0) out3[k] = nc;
}

extern "C" void kernel_launch(void* const* d_in, const int* in_sizes, int n_in,
                              void* d_out, int out_size, void* d_ws, size_t ws_size,
                              hipStream_t stream) {
    const float* z_e        = (const float*)d_in[0];
    const float* cb         = (const float*)d_in[1];
    const float* ema_count  = (const float*)d_in[2];
    const float* ema_weight = (const float*)d_in[3];
    float* out = (float*)d_out;

    float* cnorm = (float*)d_ws;                                        // K floats
    unsigned long long* packed = (unsigned long long*)((char*)d_ws + K * 4);  // NROWS u64

    // ws/out are poisoned 0xAA each call: init accumulators
    hipMemsetAsync(packed, 0xFF, NROWS * 8, stream);                    // packed = +inf
    hipMemsetAsync(out + OUT3, 0, (size_t)(K + K * D) * 4, stream);     // counts + dw = 0

    k_cnorm  <<<K / 4, 256, 0, stream>>>(cb, cnorm);
    k_argmin <<<(NROWS / TILE_R) * 2, 256, 0, stream>>>(z_e, cb, cnorm, packed);
    k_epilogue<<<NROWS / TILE_R, 256, 0, stream>>>(z_e, cb, packed,
                                                   out + OUT0, out + OUT1,
                                                   out + OUT3, out + OUT4);
    k_final  <<<(K * D) / 256, 256, 0, stream>>>(ema_count, ema_weight,
                                                 out + OUT2, out + OUT3, out + OUT4);
}

// Round 3
// 242.474 us; speedup vs baseline: 2.6622x; 2.6622x over previous
//
#include <hip/hip_runtime.h>

// Problem constants (B=16, D=128, H=32, W=32, K=8192)
#define D 128
#define HW 1024
#define NROWS 16384
#define K 8192

// d_out layout (float offsets): z_q_st | indices | new_codebook | new_count | new_weight
#define OUT0 0
#define OUT1 2097152
#define OUT2 2113536
#define OUT3 3162112
#define OUT4 3170304

typedef __attribute__((ext_vector_type(8))) _Float16 half8;
typedef __attribute__((ext_vector_type(16))) float f32x16;
typedef unsigned short u16;
typedef unsigned long long u64;

// ---- async global->LDS, 16B per lane (dst = wave-uniform base + lane*16) ----
__device__ __forceinline__ void gld16(const u16* gsrc, u16* ldst) {
    __builtin_amdgcn_global_load_lds(
        (const __attribute__((address_space(1))) unsigned int*)gsrc,
        (__attribute__((address_space(3))) unsigned int*)ldst,
        16, 0, 0);
}

// ---- cnorm: ||C_k||^2 in fp32 from the original fp32 codebook ----
__global__ __launch_bounds__(256) void k_cnorm(const float* __restrict__ cb,
                                               float* __restrict__ cnorm) {
    int lane = threadIdx.x & 63;
    int k = blockIdx.x * 4 + (threadIdx.x >> 6);
    float2 v = *(const float2*)(cb + (size_t)k * D + lane * 2);
    float s = v.x * v.x + v.y * v.y;
#pragma unroll
    for (int off = 32; off > 0; off >>= 1) s += __shfl_down(s, off);
    if (lane == 0) cnorm[k] = s;
}

// ---- split codebook -> fp16 hi/lo in MFMA-frag order ----
// layout: Bx[colgroup g][kstep ks][khalf kh][col c(256)][j(8)]
__global__ __launch_bounds__(256) void k_prep_cb(const float* __restrict__ cb,
                                                 u16* __restrict__ Bh, u16* __restrict__ Bl) {
    int gid = blockIdx.x * 256 + threadIdx.x;   // K*16 threads
    int k  = gid & (K - 1);
    int kk = gid >> 13;                         // ks*2+kh, 0..15
    const float* src = cb + (size_t)k * D + kk * 8;
    half8 h, l;
#pragma unroll
    for (int j = 0; j < 8; ++j) {
        float v = src[j];
        _Float16 hv = (_Float16)v;              // RN f32->f16
        _Float16 lv = (_Float16)(v - (float)hv);
        h[j] = hv;
        l[j] = lv;
    }
    size_t off = ((((size_t)(k >> 8) * 8 + (kk >> 1)) * 2 + (kk & 1)) * 256 + (k & 255)) * 8;
    *(half8*)(Bh + off) = h;
    *(half8*)(Bl + off) = l;
}

// ---- split z_e -> fp16 hi/lo in MFMA-frag order ----
// layout: Ax[rowgroup rg][band(4)][kstep ks][khalf kh][row(32)][j(8)]
__global__ __launch_bounds__(256) void k_prep_z(const float* __restrict__ z_e,
                                                u16* __restrict__ Ah, u16* __restrict__ Al) {
    int gid = blockIdx.x * 256 + threadIdx.x;   // NROWS*16 threads
    int n  = gid & (NROWS - 1);                 // lane-contiguous n -> coalesced reads
    int kk = gid >> 14;                         // 0..15
    int b = n >> 10, hw = n & 1023;
    const float* src = z_e + ((size_t)b * D + kk * 8) * HW + hw;
    half8 h, l;
#pragma unroll
    for (int j = 0; j < 8; ++j) {
        float v = src[(size_t)j * HW];
        _Float16 hv = (_Float16)v;
        _Float16 lv = (_Float16)(v - (float)hv);
        h[j] = hv;
        l[j] = lv;
    }
    int rg = n >> 7, band = (n >> 5) & 3, row = n & 31;
    size_t off = (((((size_t)rg * 4 + band) * 8 + (kk >> 1)) * 2 + (kk & 1)) * 32 + row) * 8;
    *(half8*)(Ah + off) = h;
    *(half8*)(Al + off) = l;
}

// ---- main: 3-pass fp16-split distance GEMM + fused argmin ----
// grid: 128 rowgroups x 4 ksplits. block: 4 waves (2 row x 2 col).
// wave tile: 64 rows x 128 cols via 32x32x16 MFMA, r2 x c4 register blocking.
// fp16 split: a = ah + al (al ~ 2^-12), passes Ah*Bl, Ah*Bh, Al*Bh;
// dropped Al*Bl ~ 1e-6 -> distances accurate to fp32 rounding level.
__global__ __launch_bounds__(256, 1) void k_argmin_mfma(
        const u16* __restrict__ Ahg, const u16* __restrict__ Alg,
        const u16* __restrict__ Bhg, const u16* __restrict__ Blg,
        const float* __restrict__ cnorm, u64* __restrict__ packed) {
    __shared__ u16 lds[65536];                  // 128 KiB
    u16* AhL = lds;                             // 16384 u16 (32 KiB)
    u16* AlL = lds + 16384;                     // 16384 u16
    u16* BL  = lds + 32768;                     // 32768 u16 (64 KiB), one half at a time

    const int tid = threadIdx.x;
    const int ln  = tid & 63;
    const int l31 = ln & 31;
    const int lh  = ln >> 5;                    // k-half select within frag
    const int wy  = (tid >> 6) & 1;             // row-wave
    const int wx  = tid >> 7;                   // col-wave

    const int rg = blockIdx.x >> 2;             // 128 row groups x 128 rows
    const int k0 = (blockIdx.x & 3) * 2048;     // k split

    // stage A once (Ah+Al, 64 KiB total)
    {
        const u16* s0 = Ahg + (size_t)rg * 16384;
        const u16* s1 = Alg + (size_t)rg * 16384;
#pragma unroll
        for (int r = 0; r < 8; ++r) {
            gld16(s0 + (r * 256 + tid) * 8, AhL + (r * 256 + tid) * 8);
            gld16(s1 + (r * 256 + tid) * 8, AlL + (r * 256 + tid) * 8);
        }
    }
    asm volatile("s_waitcnt vmcnt(0)" ::: "memory");
    __syncthreads();

    float minv[2][16];
    int   mini[2][16];
#pragma unroll
    for (int rt = 0; rt < 2; ++rt)
#pragma unroll
        for (int r = 0; r < 16; ++r) { minv[rt][r] = INFINITY; mini[rt][r] = 0; }

#pragma unroll 1
    for (int cg = 0; cg < 8; ++cg) {
        const int colbase = k0 + cg * 256;
        const size_t gB = (size_t)((k0 >> 8) + cg) * 32768;
        f32x16 acc[2][4] = {};

        // ---- stage Bl, pass 1: Ah x Bl ----
#pragma unroll
        for (int r = 0; r < 16; ++r)
            gld16(Blg + gB + (r * 256 + tid) * 8, BL + (r * 256 + tid) * 8);
        asm volatile("s_waitcnt vmcnt(0)" ::: "memory");
        __syncthreads();
#pragma unroll
        for (int ks = 0; ks < 8; ++ks) {
            half8 b[4], a[2];
#pragma unroll
            for (int c = 0; c < 4; ++c)
                b[c] = *(const half8*)(BL + (((ks * 2 + lh) * 256) + wx * 128 + c * 32 + l31) * 8);
#pragma unroll
            for (int rt = 0; rt < 2; ++rt)
                a[rt] = *(const half8*)(AhL + ((((wy * 2 + rt) * 8 + ks) * 2 + lh) * 32 + l31) * 8);
#pragma unroll
            for (int rt = 0; rt < 2; ++rt)
#pragma unroll
                for (int c = 0; c < 4; ++c)
                    acc[rt][c] = __builtin_amdgcn_mfma_f32_32x32x16_f16(a[rt], b[c], acc[rt][c], 0, 0, 0);
        }
        __syncthreads();

        // ---- stage Bh, passes 2+3: Ah x Bh, Al x Bh (B-frags shared) ----
#pragma unroll
        for (int r = 0; r < 16; ++r)
            gld16(Bhg + gB + (r * 256 + tid) * 8, BL + (r * 256 + tid) * 8);

        float cn[4];  // issue early; latency hides under waitcnt+MFMAs
#pragma unroll
        for (int c = 0; c < 4; ++c) cn[c] = cnorm[colbase + wx * 128 + c * 32 + l31];

        asm volatile("s_waitcnt vmcnt(0)" ::: "memory");
        __syncthreads();
#pragma unroll
        for (int ks = 0; ks < 8; ++ks) {
            half8 b[4], a[2], al[2];
#pragma unroll
            for (int c = 0; c < 4; ++c)
                b[c] = *(const half8*)(BL + (((ks * 2 + lh) * 256) + wx * 128 + c * 32 + l31) * 8);
#pragma unroll
            for (int rt = 0; rt < 2; ++rt) {
                a[rt]  = *(const half8*)(AhL + ((((wy * 2 + rt) * 8 + ks) * 2 + lh) * 32 + l31) * 8);
                al[rt] = *(const half8*)(AlL + ((((wy * 2 + rt) * 8 + ks) * 2 + lh) * 32 + l31) * 8);
            }
#pragma unroll
            for (int rt = 0; rt < 2; ++rt)
#pragma unroll
                for (int c = 0; c < 4; ++c)
                    acc[rt][c] = __builtin_amdgcn_mfma_f32_32x32x16_f16(a[rt], b[c], acc[rt][c], 0, 0, 0);
#pragma unroll
            for (int rt = 0; rt < 2; ++rt)
#pragma unroll
                for (int c = 0; c < 4; ++c)
                    acc[rt][c] = __builtin_amdgcn_mfma_f32_32x32x16_f16(al[rt], b[c], acc[rt][c], 0, 0, 0);
        }

        // ---- fold dist = cnorm - 2*dot into running argmin (ascending col order) ----
#pragma unroll
        for (int rt = 0; rt < 2; ++rt)
#pragma unroll
            for (int c = 0; c < 4; ++c) {
                const int colv = colbase + wx * 128 + c * 32 + l31;
#pragma unroll
                for (int r = 0; r < 16; ++r) {
                    float dist = fmaf(-2.0f, acc[rt][c][r], cn[c]);
                    if (dist < minv[rt][r]) { minv[rt][r] = dist; mini[rt][r] = colv; }
                }
            }
        __syncthreads();  // all waves done reading Bh before next cg overwrites BL
    }

    // ---- reduce across the 32 lanes sharing each output row, then atomicMin ----
#pragma unroll
    for (int rt = 0; rt < 2; ++rt)
#pragma unroll
        for (int r = 0; r < 16; ++r) {
            float v = minv[rt][r];
            int ix = mini[rt][r];
#pragma unroll
            for (int off = 1; off < 32; off <<= 1) {
                float v2 = __shfl_xor(v, off);
                int i2 = __shfl_xor(ix, off);
                if (v2 < v || (v2 == v && i2 < ix)) { v = v2; ix = i2; }
            }
            if (l31 == 0) {
                // C/D row map (m74/m101): row = (reg&3) + 8*(reg>>2) + 4*(lane>>5)
                int row = rg * 128 + wy * 64 + rt * 32 + 4 * lh + (r & 3) + 8 * (r >> 2);
                unsigned int u = __float_as_uint(v);
                u = (u & 0x80000000u) ? ~u : (u | 0x80000000u);  // monotonic encode
                u64 pk = ((u64)u << 13) | (u64)(unsigned)ix;
                atomicMin(&packed[row], pk);
            }
        }
}

// ---- epilogue: indices, z_q_st, counts, dw ----
__global__ __launch_bounds__(256) void k_epilogue(const float* __restrict__ z_e,
                                                  const float* __restrict__ cb,
                                                  const u64* __restrict__ packed,
                                                  float* __restrict__ out0,
                                                  float* __restrict__ out1,
                                                  float* __restrict__ counts,
                                                  float* __restrict__ dw) {
    __shared__ int idxS[64];
    const int tid = threadIdx.x;
    const int n0 = blockIdx.x * 64;
    const int bb = n0 >> 10, p0 = n0 & 1023;

    if (tid < 64) {
        int ix = (int)(packed[n0 + tid] & 0x1FFFull);
        idxS[tid] = ix;
        out1[n0 + tid] = (float)ix;
        atomicAdd(&counts[ix], 1.0f);
    }
    __syncthreads();

    const float* zb = z_e + (size_t)bb * (D * HW) + p0;
    float* ob = out0 + (size_t)bb * (D * HW) + p0;

    for (int i = tid; i < 64 * D; i += 256) {
        int d = i >> 6, r = i & 63;
        float z = zb[(size_t)d * HW + r];
        float c = cb[(size_t)idxS[r] * D + d];
        ob[(size_t)d * HW + r] = z + (c - z);
    }
    for (int i = tid; i < 64 * D; i += 256) {
        int r = i >> 7, d = i & 127;
        atomicAdd(&dw[(size_t)idxS[r] * D + d], zb[(size_t)d * HW + r]);
    }
}

__global__ __launch_bounds__(256) void k_final(const float* __restrict__ ema_count,
                                               const float* __restrict__ ema_weight,
                                               float* __restrict__ out2,
                                               float* __restrict__ out3,
                                               float* __restrict__ out4) {
    int gid = blockIdx.x * 256 + threadIdx.x;   // over K*D
    int k = gid >> 7, d = gid & 127;
    float cnt_raw = out3[k];
    float dw_raw = out4[gid];
    __syncthreads();
    float nc = 0.99f * ema_count[k] + 0.01f * cnt_raw;
    float nw = 0.99f * ema_weight[gid] + 0.01f * dw_raw;
    out4[gid] = nw;
    out2[gid] = nw / fmaxf(nc, 1.0f);
    if (d == 0) out3[k] = nc;
}

extern "C" void kernel_launch(void* const* d_in, const int* in_sizes, int n_in,
                              void* d_out, int out_size, void* d_ws, size_t ws_size,
                              hipStream_t stream) {
    const float* z_e        = (const float*)d_in[0];
    const float* cb         = (const float*)d_in[1];
    const float* ema_count  = (const float*)d_in[2];
    const float* ema_weight = (const float*)d_in[3];
    float* out = (float*)d_out;

    float* cnorm = (float*)d_ws;                                   // K floats
    u64* packed = (u64*)((char*)d_ws + K * 4);                     // NROWS u64

    // fp16-split scratch lives in out regions that are rewritten later:
    // out0 (8 MB) hosts Ah|Al, out2 (4 MB) hosts Bh|Bl during the GEMM.
    u16* Ahg = (u16*)(out + OUT0);
    u16* Alg = Ahg + (size_t)NROWS * D;
    u16* Bhg = (u16*)(out + OUT2);
    u16* Blg = Bhg + (size_t)K * D;

    hipMemsetAsync(packed, 0xFF, NROWS * 8, stream);               // packed = +inf
    hipMemsetAsync(out + OUT3, 0, (size_t)(K + K * D) * 4, stream);// counts + dw = 0

    k_cnorm      <<<K / 4,            256, 0, stream>>>(cb, cnorm);
    k_prep_cb    <<<K * 16 / 256,     256, 0, stream>>>(cb, Bhg, Blg);
    k_prep_z     <<<NROWS * 16 / 256, 256, 0, stream>>>(z_e, Ahg, Alg);
    k_argmin_mfma<<<512,              256, 0, stream>>>(Ahg, Alg, Bhg, Blg, cnorm, packed);
    k_epilogue   <<<NROWS / 64,       256, 0, stream>>>(z_e, cb, packed,
                                                        out + OUT0, out + OUT1,
                                                        out + OUT3, out + OUT4);
    k_final      <<<(K * D) / 256,    256, 0, stream>>>(ema_count, ema_weight,
                                                        out + OUT2, out + OUT3, out + OUT4);
}

// Round 4
// 220.782 us; speedup vs baseline: 2.9237x; 1.0982x over previous
//
#include <hip/hip_runtime.h>

// Problem constants (B=16, D=128, H=32, W=32, K=8192)
#define D 128
#define HW 1024
#define NROWS 16384
#define K 8192
#define NU 16   // 128-col units per block (K/4 split / 128)

// d_out layout (float offsets): z_q_st | indices | new_codebook | new_count | new_weight
#define OUT0 0
#define OUT1 2097152
#define OUT2 2113536
#define OUT3 3162112
#define OUT4 3170304

typedef __attribute__((ext_vector_type(8))) _Float16 half8;
typedef __attribute__((ext_vector_type(16))) float f32x16;
typedef unsigned short u16;
typedef unsigned long long u64;

// ---- async global->LDS, 16B per lane (dst = wave-uniform base + lane*16) ----
__device__ __forceinline__ void gld16(const u16* gsrc, u16* ldst) {
    __builtin_amdgcn_global_load_lds(
        (const __attribute__((address_space(1))) unsigned int*)gsrc,
        (__attribute__((address_space(3))) unsigned int*)ldst,
        16, 0, 0);
}

// ---- fused: split codebook -> fp16 hi/lo (unit-interleaved layout) + cnorm ----
// B layout: [unit g(64)][ Bh: [kk(16)][col(128)][j(8)] | Bl: same ]  (64 KiB/unit)
__global__ __launch_bounds__(256) void k_prep_cb(const float* __restrict__ cb,
                                                 u16* __restrict__ Bg,
                                                 float* __restrict__ cnorm) {
    int tid = threadIdx.x;
    int kk = tid & 15;
    int k = blockIdx.x * 16 + (tid >> 4);
    const float* src = cb + (size_t)k * D + kk * 8;
    half8 h, l;
    float s = 0.f;
#pragma unroll
    for (int j = 0; j < 8; ++j) {
        float v = src[j];
        s += v * v;
        _Float16 hv = (_Float16)v;              // RN f32->f16
        _Float16 lv = (_Float16)(v - (float)hv);
        h[j] = hv;
        l[j] = lv;
    }
    int g = k >> 7, col = k & 127;
    size_t offH = (size_t)g * 32768 + ((size_t)kk * 128 + col) * 8;
    *(half8*)((_Float16*)Bg + offH) = h;
    *(half8*)((_Float16*)Bg + offH + 16384) = l;
    // cnorm: reduce over the 16 kk-lanes of this k
#pragma unroll
    for (int off = 8; off > 0; off >>= 1) s += __shfl_down(s, off);
    if (kk == 0) cnorm[k] = s;
}

// ---- split z_e -> fp16 hi/lo in MFMA-frag order ----
// layout: Ax[rowgroup rg][band(4)][ks(8)][kh(2)][row(32)][j(8)]
__global__ __launch_bounds__(256) void k_prep_z(const float* __restrict__ z_e,
                                                u16* __restrict__ Ah, u16* __restrict__ Al) {
    int gid = blockIdx.x * 256 + threadIdx.x;   // NROWS*16 threads
    int n  = gid & (NROWS - 1);                 // lane-contiguous n -> coalesced reads
    int kk = gid >> 14;                         // 0..15
    int b = n >> 10, hw = n & 1023;
    const float* src = z_e + ((size_t)b * D + kk * 8) * HW + hw;
    half8 h, l;
#pragma unroll
    for (int j = 0; j < 8; ++j) {
        float v = src[(size_t)j * HW];
        _Float16 hv = (_Float16)v;
        _Float16 lv = (_Float16)(v - (float)hv);
        h[j] = hv;
        l[j] = lv;
    }
    int rg = n >> 7, band = (n >> 5) & 3, row = n & 31;
    size_t off = (((((size_t)rg * 4 + band) * 8 + (kk >> 1)) * 2 + (kk & 1)) * 32 + row) * 8;
    *(half8*)(Ah + off) = h;
    *(half8*)(Al + off) = l;
}

// ---- main: 3-pass fp16-split distance GEMM + fused argmin ----
// grid: 128 rowgroups x 4 ksplits, 512 threads (8 waves: wy 0..3 x wx 0..1).
// Wave tile: 32 rows x 64 cols; A-frags (Ah+Al) pinned in VGPRs; B staged in
// 128-col units, double-buffered via global_load_lds with raw s_barrier +
// explicit vmcnt so the next unit's prefetch stays in flight across barriers.
__global__ __launch_bounds__(512, 2) void k_argmin_mfma(
        const u16* __restrict__ Ahg, const u16* __restrict__ Alg,
        const u16* __restrict__ Bg,
        const float* __restrict__ cnorm, u64* __restrict__ packed) {
    __shared__ u16 lds[2][32768];               // 2 x 64 KiB

    const int tid = threadIdx.x;
    const int ln  = tid & 63;
    const int l31 = ln & 31;
    const int lh  = ln >> 5;                    // k-half select within frag
    const int wv  = tid >> 6;                   // 0..7
    const int wy  = wv & 3;                     // row band 0..3
    const int wx  = wv >> 2;                    // col half 0..1

    const int rg = blockIdx.x >> 2;             // 128 row groups x 128 rows
    const int k0 = (blockIdx.x & 3) * 2048;     // k split
    const int g0 = k0 >> 7;                     // first B-unit

    // ---- A fragments -> registers (read once from global; 64 VGPRs) ----
    half8 Ah[8], Al[8];
#pragma unroll
    for (int ks = 0; ks < 8; ++ks) {
        size_t off = ((((size_t)(rg * 4 + wy) * 8 + ks) * 2 + lh) * 32 + l31) * 8;
        Ah[ks] = *(const half8*)((const _Float16*)Ahg + off);
        Al[ks] = *(const half8*)((const _Float16*)Alg + off);
    }

    // ---- prologue: stage unit 0 ----
    {
        const u16* src = Bg + (size_t)g0 * 32768;
#pragma unroll
        for (int r = 0; r < 8; ++r)
            gld16(src + ((size_t)r * 512 + tid) * 8, lds[0] + (r * 512 + tid) * 8);
    }

    float minv[16];
    int   mini[16];
#pragma unroll
    for (int r = 0; r < 16; ++r) { minv[r] = INFINITY; mini[r] = 0; }

#pragma unroll 1
    for (int u = 0; u < NU; ++u) {
        const u16* buf = lds[u & 1];
        const int colbase = k0 + u * 128;
        const int c0 = colbase + wx * 64 + l31;

        // cn loads first (older than the prefetch below -> covered by vmcnt(8))
        float cn0 = cnorm[c0];
        float cn1 = cnorm[c0 + 32];

        if (u + 1 < NU) {
            // prefetch next unit into the other buffer; keep it in flight
            const u16* src = Bg + (size_t)(g0 + u + 1) * 32768;
            u16* dst = lds[(u + 1) & 1];
#pragma unroll
            for (int r = 0; r < 8; ++r)
                gld16(src + ((size_t)r * 512 + tid) * 8, dst + (r * 512 + tid) * 8);
            // wait for *this* unit's stage (8 newer prefetch ops may stay outstanding)
            asm volatile("s_waitcnt vmcnt(8)" ::: "memory");
        } else {
            asm volatile("s_waitcnt vmcnt(0)" ::: "memory");
        }
        asm volatile("s_barrier" ::: "memory");   // all waves' slices of unit u staged

        f32x16 acc0 = {}, acc1 = {};
        const u16* bh = buf;
        const u16* bl = buf + 16384;

        // pass 1: Ah x Bl
#pragma unroll
        for (int ks = 0; ks < 8; ++ks) {
            const int bo = ((ks * 2 + lh) * 128 + wx * 64 + l31) * 8;
            half8 b0 = *(const half8*)((const _Float16*)bl + bo);
            half8 b1 = *(const half8*)((const _Float16*)bl + bo + 256);
            acc0 = __builtin_amdgcn_mfma_f32_32x32x16_f16(Ah[ks], b0, acc0, 0, 0, 0);
            acc1 = __builtin_amdgcn_mfma_f32_32x32x16_f16(Ah[ks], b1, acc1, 0, 0, 0);
        }
        // passes 2+3: Ah x Bh, Al x Bh (B-frags shared)
#pragma unroll
        for (int ks = 0; ks < 8; ++ks) {
            const int bo = ((ks * 2 + lh) * 128 + wx * 64 + l31) * 8;
            half8 b0 = *(const half8*)((const _Float16*)bh + bo);
            half8 b1 = *(const half8*)((const _Float16*)bh + bo + 256);
            acc0 = __builtin_amdgcn_mfma_f32_32x32x16_f16(Ah[ks], b0, acc0, 0, 0, 0);
            acc1 = __builtin_amdgcn_mfma_f32_32x32x16_f16(Ah[ks], b1, acc1, 0, 0, 0);
            acc0 = __builtin_amdgcn_mfma_f32_32x32x16_f16(Al[ks], b0, acc0, 0, 0, 0);
            acc1 = __builtin_amdgcn_mfma_f32_32x32x16_f16(Al[ks], b1, acc1, 0, 0, 0);
        }

        // fold dist = cnorm - 2*dot into running argmin (ascending col order)
#pragma unroll
        for (int r = 0; r < 16; ++r) {
            float d0 = fmaf(-2.0f, acc0[r], cn0);
            float d1 = fmaf(-2.0f, acc1[r], cn1);
            if (d0 < minv[r]) { minv[r] = d0; mini[r] = c0; }
            if (d1 < minv[r]) { minv[r] = d1; mini[r] = c0 + 32; }
        }
        // all reads of buf[u&1] consumed (MFMA data-deps drained lgkm);
        // raw barrier so next iteration may overwrite buf[(u+1)&1]'s sibling
        asm volatile("s_barrier" ::: "memory");
    }

    // ---- reduce across the 32 l31-lanes sharing each output row ----
#pragma unroll
    for (int r = 0; r < 16; ++r) {
        float v = minv[r];
        int ix = mini[r];
#pragma unroll
        for (int off = 1; off < 32; off <<= 1) {
            float v2 = __shfl_xor(v, off);
            int i2 = __shfl_xor(ix, off);
            if (v2 < v || (v2 == v && i2 < ix)) { v = v2; ix = i2; }
        }
        if (l31 == 0) {
            // C/D row map (m74/m101): row = (reg&3) + 8*(reg>>2) + 4*(lane>>5)
            int row = rg * 128 + wy * 32 + 4 * lh + (r & 3) + 8 * (r >> 2);
            unsigned int uenc = __float_as_uint(v);
            uenc = (uenc & 0x80000000u) ? ~uenc : (uenc | 0x80000000u);  // monotonic
            u64 pk = ((u64)uenc << 13) | (u64)(unsigned)ix;
            atomicMin(&packed[row], pk);
        }
    }
}

// ---- epilogue: indices, z_q_st, counts, dw ----
__global__ __launch_bounds__(256) void k_epilogue(const float* __restrict__ z_e,
                                                  const float* __restrict__ cb,
                                                  const u64* __restrict__ packed,
                                                  float* __restrict__ out0,
                                                  float* __restrict__ out1,
                                                  float* __restrict__ counts,
                                                  float* __restrict__ dw) {
    __shared__ int idxS[64];
    const int tid = threadIdx.x;
    const int n0 = blockIdx.x * 64;
    const int bb = n0 >> 10, p0 = n0 & 1023;

    if (tid < 64) {
        int ix = (int)(packed[n0 + tid] & 0x1FFFull);
        idxS[tid] = ix;
        out1[n0 + tid] = (float)ix;
        atomicAdd(&counts[ix], 1.0f);
    }
    __syncthreads();

    const float* zb = z_e + (size_t)bb * (D * HW) + p0;
    float* ob = out0 + (size_t)bb * (D * HW) + p0;

    for (int i = tid; i < 64 * D; i += 256) {
        int d = i >> 6, r = i & 63;
        float z = zb[(size_t)d * HW + r];
        float c = cb[(size_t)idxS[r] * D + d];
        ob[(size_t)d * HW + r] = z + (c - z);
    }
    for (int i = tid; i < 64 * D; i += 256) {
        int r = i >> 7, d = i & 127;
        atomicAdd(&dw[(size_t)idxS[r] * D + d], zb[(size_t)d * HW + r]);
    }
}

__global__ __launch_bounds__(256) void k_final(const float* __restrict__ ema_count,
                                               const float* __restrict__ ema_weight,
                                               float* __restrict__ out2,
                                               float* __restrict__ out3,
                                               float* __restrict__ out4) {
    int gid = blockIdx.x * 256 + threadIdx.x;   // over K*D
    int k = gid >> 7, d = gid & 127;
    float cnt_raw = out3[k];
    float dw_raw = out4[gid];
    __syncthreads();
    float nc = 0.99f * ema_count[k] + 0.01f * cnt_raw;
    float nw = 0.99f * ema_weight[gid] + 0.01f * dw_raw;
    out4[gid] = nw;
    out2[gid] = nw / fmaxf(nc, 1.0f);
    if (d == 0) out3[k] = nc;
}

extern "C" void kernel_launch(void* const* d_in, const int* in_sizes, int n_in,
                              void* d_out, int out_size, void* d_ws, size_t ws_size,
                              hipStream_t stream) {
    const float* z_e        = (const float*)d_in[0];
    const float* cb         = (const float*)d_in[1];
    const float* ema_count  = (const float*)d_in[2];
    const float* ema_weight = (const float*)d_in[3];
    float* out = (float*)d_out;

    float* cnorm = (float*)d_ws;                                   // K floats
    u64* packed = (u64*)((char*)d_ws + K * 4);                     // NROWS u64

    // fp16-split scratch lives in out regions rewritten later:
    // out0 (8 MB) hosts Ah|Al, out2 (4 MB) hosts the unit-interleaved B.
    u16* Ahg = (u16*)(out + OUT0);
    u16* Alg = Ahg + (size_t)NROWS * D;
    u16* Bg  = (u16*)(out + OUT2);                                 // 64 units x 64 KiB

    hipMemsetAsync(packed, 0xFF, NROWS * 8, stream);               // packed = +inf
    hipMemsetAsync(out + OUT3, 0, (size_t)(K + K * D) * 4, stream);// counts + dw = 0

    k_prep_cb    <<<K / 16,           256, 0, stream>>>(cb, Bg, cnorm);
    k_prep_z     <<<NROWS * 16 / 256, 256, 0, stream>>>(z_e, Ahg, Alg);
    k_argmin_mfma<<<512,              512, 0, stream>>>(Ahg, Alg, Bg, cnorm, packed);
    k_epilogue   <<<NROWS / 64,       256, 0, stream>>>(z_e, cb, packed,
                                                        out + OUT0, out + OUT1,
                                                        out + OUT3, out + OUT4);
    k_final      <<<(K * D) / 256,    256, 0, stream>>>(ema_count, ema_weight,
                                                        out + OUT2, out + OUT3, out + OUT4);
}

// Round 5
// 205.603 us; speedup vs baseline: 3.1396x; 1.0738x over previous
//
#include <hip/hip_runtime.h>

// Problem constants (B=16, D=128, H=32, W=32, K=8192)
#define D 128
#define HW 1024
#define NROWS 16384
#define K 8192
#define NU 32   // 64-col units per block (2048-col k-split / 64)

// d_out layout (float offsets): z_q_st | indices | new_codebook | new_count | new_weight
#define OUT0 0
#define OUT1 2097152
#define OUT2 2113536
#define OUT3 3162112
#define OUT4 3170304

typedef __attribute__((ext_vector_type(8))) _Float16 half8;
typedef __attribute__((ext_vector_type(16))) float f32x16;
typedef unsigned short u16;
typedef unsigned long long u64;

// ---- async global->LDS, 16B per lane (dst = wave-uniform base + lane*16) ----
__device__ __forceinline__ void gld16(const u16* gsrc, u16* ldst) {
    __builtin_amdgcn_global_load_lds(
        (const __attribute__((address_space(1))) unsigned int*)gsrc,
        (__attribute__((address_space(3))) unsigned int*)ldst,
        16, 0, 0);
}

// ---- fused prep: blocks [0,512) codebook-split + cnorm + dw-zero;
//      blocks [512,1536) z-split + packed-init + counts-zero ----
// B layout: [unit g(128)][ Bh: [kk(16)][col(64)][j(8)] | Bl: same ] (32 KiB/unit)
// A layout: [rg(128)][band(4)][ks(8)][kh(2)][row(32)][j(8)]
__global__ __launch_bounds__(256) void k_prep(const float* __restrict__ cb,
                                              const float* __restrict__ z_e,
                                              u16* __restrict__ Bg,
                                              float* __restrict__ cnorm,
                                              u16* __restrict__ Ah, u16* __restrict__ Al,
                                              u64* __restrict__ packed,
                                              float* __restrict__ counts,
                                              float* __restrict__ dw) {
    const int tid = threadIdx.x;
    if (blockIdx.x < 512) {
        int kk = tid & 15;
        int k = blockIdx.x * 16 + (tid >> 4);
        const float* src = cb + (size_t)k * D + kk * 8;
        half8 h, l;
        float s = 0.f;
#pragma unroll
        for (int j = 0; j < 8; ++j) {
            float v = src[j];
            s += v * v;
            _Float16 hv = (_Float16)v;              // RN f32->f16
            _Float16 lv = (_Float16)(v - (float)hv);
            h[j] = hv;
            l[j] = lv;
        }
        int g = k >> 6, col = k & 63;
        size_t offH = (size_t)g * 16384 + ((size_t)kk * 64 + col) * 8;
        *(half8*)((_Float16*)Bg + offH) = h;
        *(half8*)((_Float16*)Bg + offH + 8192) = l;
#pragma unroll
        for (int off = 8; off > 0; off >>= 1) s += __shfl_down(s, off);
        if (kk == 0) cnorm[k] = s;
        // zero dw: 131072 threads x 8 floats = K*D exactly
        float4 z4 = {0.f, 0.f, 0.f, 0.f};
        size_t zi = ((size_t)blockIdx.x * 256 + tid) * 8;
        *(float4*)(dw + zi) = z4;
        *(float4*)(dw + zi + 4) = z4;
    } else {
        int gid = (blockIdx.x - 512) * 256 + tid;   // NROWS*16 threads
        int n  = gid & (NROWS - 1);                 // lane-contiguous n -> coalesced
        int kk = gid >> 14;                         // 0..15
        int b = n >> 10, hw = n & 1023;
        const float* src = z_e + ((size_t)b * D + kk * 8) * HW + hw;
        half8 h, l;
#pragma unroll
        for (int j = 0; j < 8; ++j) {
            float v = src[(size_t)j * HW];
            _Float16 hv = (_Float16)v;
            _Float16 lv = (_Float16)(v - (float)hv);
            h[j] = hv;
            l[j] = lv;
        }
        int rg = n >> 7, band = (n >> 5) & 3, row = n & 31;
        size_t off = (((((size_t)rg * 4 + band) * 8 + (kk >> 1)) * 2 + (kk & 1)) * 32 + row) * 8;
        *(half8*)(Ah + off) = h;
        *(half8*)(Al + off) = l;
        if (kk == 0) {
            packed[n] = ~0ull;                      // +inf sentinel
            if (n < K) counts[n] = 0.f;
        }
    }
}

// ---- main: 3-pass fp16-split distance GEMM + fused argmin ----
// grid: 128 rowgroups x 4 ksplits, 512 threads (8 waves: wy 0..3 x wx 0..1).
// Wave tile: 32 rows x 32 cols; A-frags pinned in VGPRs; B in 64-col units,
// 2x32 KiB LDS dbuf (-> 2 blocks/CU, 4 waves/SIMD) with in-flight prefetch
// across raw s_barrier via explicit vmcnt(4).
__global__ __launch_bounds__(512, 4) void k_argmin_mfma(
        const u16* __restrict__ Ahg, const u16* __restrict__ Alg,
        const u16* __restrict__ Bg,
        const float* __restrict__ cnorm, u64* __restrict__ packed) {
    __shared__ u16 lds[2][16384];               // 2 x 32 KiB

    const int tid = threadIdx.x;
    const int ln  = tid & 63;
    const int l31 = ln & 31;
    const int lh  = ln >> 5;                    // k-half select within frag
    const int wv  = tid >> 6;                   // 0..7
    const int wy  = wv & 3;                     // row band 0..3
    const int wx  = wv >> 2;                    // col half 0..1

    const int rg = blockIdx.x >> 2;             // 128 row groups x 128 rows
    const int k0 = (blockIdx.x & 3) * 2048;     // k split
    const int g0 = k0 >> 6;                     // first 64-col B-unit

    // ---- A fragments -> registers (read once from global; 64 VGPRs) ----
    half8 Ah[8], Al[8];
#pragma unroll
    for (int ks = 0; ks < 8; ++ks) {
        size_t off = ((((size_t)(rg * 4 + wy) * 8 + ks) * 2 + lh) * 32 + l31) * 8;
        Ah[ks] = *(const half8*)((const _Float16*)Ahg + off);
        Al[ks] = *(const half8*)((const _Float16*)Alg + off);
    }

    // ---- prologue: stage unit 0 (32 KiB, 4 gld16/thread) ----
    {
        const u16* src = Bg + (size_t)g0 * 16384;
#pragma unroll
        for (int r = 0; r < 4; ++r)
            gld16(src + ((size_t)r * 512 + tid) * 8, lds[0] + (r * 512 + tid) * 8);
    }

    float minv[16];
    int   mini[16];
#pragma unroll
    for (int r = 0; r < 16; ++r) { minv[r] = INFINITY; mini[r] = 0; }

#pragma unroll 1
    for (int u = 0; u < NU; ++u) {
        const u16* buf = lds[u & 1];
        const int c0 = k0 + u * 64 + wx * 32 + l31;

        // cn load first (older than the prefetch -> completed once vmcnt<=4)
        float cn0 = cnorm[c0];

        if (u + 1 < NU) {
            const u16* src = Bg + (size_t)(g0 + u + 1) * 16384;
            u16* dst = lds[(u + 1) & 1];
#pragma unroll
            for (int r = 0; r < 4; ++r)
                gld16(src + ((size_t)r * 512 + tid) * 8, dst + (r * 512 + tid) * 8);
            // wait for *this* unit's stage; next unit's 4 loads stay in flight
            asm volatile("s_waitcnt vmcnt(4)" ::: "memory");
        } else {
            asm volatile("s_waitcnt vmcnt(0)" ::: "memory");
        }
        asm volatile("s_barrier" ::: "memory");

        f32x16 acc = {};
        const _Float16* bh = (const _Float16*)buf;
        const _Float16* bl = bh + 8192;

        // pass 1: Ah x Bl
#pragma unroll
        for (int ks = 0; ks < 8; ++ks) {
            const int bo = ((ks * 2 + lh) * 64 + wx * 32 + l31) * 8;
            half8 b0 = *(const half8*)(bl + bo);
            acc = __builtin_amdgcn_mfma_f32_32x32x16_f16(Ah[ks], b0, acc, 0, 0, 0);
        }
        // passes 2+3: Ah x Bh, Al x Bh (B-frag shared)
#pragma unroll
        for (int ks = 0; ks < 8; ++ks) {
            const int bo = ((ks * 2 + lh) * 64 + wx * 32 + l31) * 8;
            half8 b0 = *(const half8*)(bh + bo);
            acc = __builtin_amdgcn_mfma_f32_32x32x16_f16(Ah[ks], b0, acc, 0, 0, 0);
            acc = __builtin_amdgcn_mfma_f32_32x32x16_f16(Al[ks], b0, acc, 0, 0, 0);
        }

        // fold dist = cnorm - 2*dot into running argmin
#pragma unroll
        for (int r = 0; r < 16; ++r) {
            float d0 = fmaf(-2.0f, acc[r], cn0);
            if (d0 < minv[r]) { minv[r] = d0; mini[r] = c0; }
        }
        // all waves done reading buf before its sibling is overwritten next iter
        asm volatile("s_barrier" ::: "memory");
    }

    // ---- reduce across the 32 l31-lanes sharing each output row ----
#pragma unroll
    for (int r = 0; r < 16; ++r) {
        float v = minv[r];
        int ix = mini[r];
#pragma unroll
        for (int off = 1; off < 32; off <<= 1) {
            float v2 = __shfl_xor(v, off);
            int i2 = __shfl_xor(ix, off);
            if (v2 < v || (v2 == v && i2 < ix)) { v = v2; ix = i2; }
        }
        if (l31 == 0) {
            // C/D row map (m74/m101): row = (reg&3) + 8*(reg>>2) + 4*(lane>>5)
            int row = rg * 128 + wy * 32 + 4 * lh + (r & 3) + 8 * (r >> 2);
            unsigned int uenc = __float_as_uint(v);
            uenc = (uenc & 0x80000000u) ? ~uenc : (uenc | 0x80000000u);  // monotonic
            u64 pk = ((u64)uenc << 13) | (u64)(unsigned)ix;
            atomicMin(&packed[row], pk);
        }
    }
}

// ---- epilogue: indices, z_q_st, counts, dw ----
__global__ __launch_bounds__(256) void k_epilogue(const float* __restrict__ z_e,
                                                  const float* __restrict__ cb,
                                                  const u64* __restrict__ packed,
                                                  float* __restrict__ out0,
                                                  float* __restrict__ out1,
                                                  float* __restrict__ counts,
                                                  float* __restrict__ dw) {
    __shared__ int idxS[64];
    const int tid = threadIdx.x;
    const int n0 = blockIdx.x * 64;
    const int bb = n0 >> 10, p0 = n0 & 1023;

    if (tid < 64) {
        int ix = (int)(packed[n0 + tid] & 0x1FFFull);
        idxS[tid] = ix;
        out1[n0 + tid] = (float)ix;
        atomicAdd(&counts[ix], 1.0f);
    }
    __syncthreads();

    const float* zb = z_e + (size_t)bb * (D * HW) + p0;
    float* ob = out0 + (size_t)bb * (D * HW) + p0;

    for (int i = tid; i < 64 * D; i += 256) {
        int d = i >> 6, r = i & 63;
        float z = zb[(size_t)d * HW + r];
        float c = cb[(size_t)idxS[r] * D + d];
        ob[(size_t)d * HW + r] = z + (c - z);
    }
    for (int i = tid; i < 64 * D; i += 256) {
        int r = i >> 7, d = i & 127;
        atomicAdd(&dw[(size_t)idxS[r] * D + d], zb[(size_t)d * HW + r]);
    }
}

__global__ __launch_bounds__(256) void k_final(const float* __restrict__ ema_count,
                                               const float* __restrict__ ema_weight,
                                               float* __restrict__ out2,
                                               float* __restrict__ out3,
                                               float* __restrict__ out4) {
    int gid = blockIdx.x * 256 + threadIdx.x;   // over K*D
    int k = gid >> 7, d = gid & 127;
    float cnt_raw = out3[k];
    float dw_raw = out4[gid];
    __syncthreads();
    float nc = 0.99f * ema_count[k] + 0.01f * cnt_raw;
    float nw = 0.99f * ema_weight[gid] + 0.01f * dw_raw;
    out4[gid] = nw;
    out2[gid] = nw / fmaxf(nc, 1.0f);
    if (d == 0) out3[k] = nc;
}

extern "C" void kernel_launch(void* const* d_in, const int* in_sizes, int n_in,
                              void* d_out, int out_size, void* d_ws, size_t ws_size,
                              hipStream_t stream) {
    const float* z_e        = (const float*)d_in[0];
    const float* cb         = (const float*)d_in[1];
    const float* ema_count  = (const float*)d_in[2];
    const float* ema_weight = (const float*)d_in[3];
    float* out = (float*)d_out;

    float* cnorm = (float*)d_ws;                                   // K floats
    u64* packed = (u64*)((char*)d_ws + K * 4);                     // NROWS u64

    // fp16-split scratch lives in out regions rewritten later:
    // out0 (8 MB) hosts Ah|Al, out2 (4 MB) hosts the unit-interleaved B.
    u16* Ahg = (u16*)(out + OUT0);
    u16* Alg = Ahg + (size_t)NROWS * D;
    u16* Bg  = (u16*)(out + OUT2);                                 // 128 units x 32 KiB

    k_prep       <<<1536,          256, 0, stream>>>(cb, z_e, Bg, cnorm, Ahg, Alg,
                                                     packed, out + OUT3, out + OUT4);
    k_argmin_mfma<<<512,           512, 0, stream>>>(Ahg, Alg, Bg, cnorm, packed);
    k_epilogue   <<<NROWS / 64,    256, 0, stream>>>(z_e, cb, packed,
                                                     out + OUT0, out + OUT1,
                                                     out + OUT3, out + OUT4);
    k_final      <<<(K * D) / 256, 256, 0, stream>>>(ema_count, ema_weight,
                                                     out + OUT2, out + OUT3, out + OUT4);
}